// Round 21
// baseline (529.942 us; speedup 1.0000x reference)
//
#include <hip/hip_runtime.h>
#include <hip/hip_bf16.h>
#include <stdint.h>

// SNN forward v7: FUSED pipeline (2 kernels).
//   prep: spikes -> i8 S' (t-reordered: row' = b*64+t) + maskR + W digit-pack.
//   gemm_fused: 2-plane i8 MFMA GEMM (ring-3, depth-2, 1 barrier/iter) whose
//     M-tile holds complete scan columns (2 b x 64 t) -> f32 LIF scan runs in
//     the EPILOGUE (LDS-staged, 32 lanes/wave/layer), writes spk/mem directly,
//     and inline-fixes flagged columns with the r14-validated OpenBLAS-order
//     bit-skip chain (ascending-k, KC=384 folds) -- bit-identical to ref.
// Eliminates the 256MB cur round-trip + 2 kernel launches vs v6.
// EPS=3e-4 Hoeffding-certified for the 2^20 quantization error (do not lower).
//
// d_out (f32): [spk1 | mem1 | spk2 | mem2] x 16777216.
// d_ws: Bp 8MB | S' 32MB | maskR 4MB.

#define REGION 16777216
#define BN_ELEMS 262144
#define FLAG_EPS 3e-4f

typedef __attribute__((ext_vector_type(4))) int v4i;

typedef __attribute__((address_space(1))) const void gvoid_t;
typedef __attribute__((address_space(3))) void svoid_t;

__device__ __forceinline__ void gload_lds16(const void* g, void* l) {
  __builtin_amdgcn_global_load_lds((gvoid_t*)g, (svoid_t*)l, 16, 0, 0);
}

// ---- fused prep: blocks 0..2047 cvt(t-reorder)+mask; 2048..18431 digit-pack ----
__global__ void prep_kernel(const float* __restrict__ spikes, int* __restrict__ s4,
                            unsigned long long* __restrict__ maskR,
                            const float* __restrict__ W1, const float* __restrict__ W2,
                            signed char* __restrict__ Bp) {
  int blk = blockIdx.x;
  if (blk < 2048) {
    int id = blk * 256 + threadIdx.x;         // 16384 rows * 32 chunks
    int row = id >> 5, c = id & 31;           // row = t*256 + b
    int t = row >> 8, b = row & 255;
    int rowp = b * 64 + t;                    // reordered row'
    const float4* p = (const float4*)(spikes + (long long)row * 2048 + c * 64);
    unsigned long long m = 0;
    int* sd = s4 + (rowp * 2048 + c * 64) / 4;
#pragma unroll
    for (int q = 0; q < 16; ++q) {
      float4 v = p[q];
      int b0 = (v.x != 0.f), b1 = (v.y != 0.f), b2 = (v.z != 0.f), b3 = (v.w != 0.f);
      sd[q] = b0 | (b1 << 8) | (b2 << 16) | (b3 << 24);
      m |= (unsigned long long)b0 << (4 * q);
      m |= (unsigned long long)b1 << (4 * q + 1);
      m |= (unsigned long long)b2 << (4 * q + 2);
      m |= (unsigned long long)b3 << (4 * q + 3);
    }
    maskR[(long long)row * 32 + c] = m;       // masks stay ORIGINAL-row indexed
  } else {
    int idx = (blk - 2048) * 256 + threadIdx.x;   // 2048*2048
    int n = idx >> 11, k = idx & 2047;
    float w = (n < 1024) ? W1[n * 2048 + k] : W2[(n - 1024) * 2048 + k];
    int V = (int)rintf(w * 1048576.0f);       // 2^20; |V| <= 23270
    int d0 = ((V + 128) & 255) - 128;
    int d1 = (V - d0) >> 8;                   // |d1| <= 91
    signed char* row = Bp + (long long)n * 4096;
    row[k]        = (signed char)d1;   // seg 0
    row[2048 + k] = (signed char)d0;   // seg 1
  }
}

// ---- fused GEMM + scan + inline fixup ----
__global__ __launch_bounds__(512) void gemm_fused(const signed char* __restrict__ S,
                                                  const signed char* __restrict__ Bp,
                                                  const unsigned long long* __restrict__ maskR,
                                                  const float* __restrict__ W1,
                                                  const float* __restrict__ W2,
                                                  float* __restrict__ out) {
  __shared__ __align__(16) signed char smem[73728];   // As|Bs0|Bs1, 24KB each
  signed char* As  = smem;
  signed char* Bs0 = smem + 24576;
  signed char* Bs1 = smem + 49152;
  const int tid = threadIdx.x;
  const int wv = tid >> 6, ln = tid & 63;

  int bid = blockIdx.x;                        // XCD swizzle (1024 = 8*128)
  int swz = (bid & 7) * 128 + (bid >> 3);
  const int bm = swz >> 3;    // 0..127
  const int bn = swz & 7;     // 0..7
  const int wr = wv >> 2, wc = wv & 3;         // 2M x 4N waves

  const int srow = wv * 16 + (ln >> 2);
  const int scolb = ((ln & 3) ^ ((srow >> 1) & 3)) * 16;   // pre-inverse swizzle
  const signed char* aSrc  = S  + (long long)(bm * 128 + srow) * 2048 + scolb;
  const signed char* b0Src = Bp + (long long)(bn * 128 + srow) * 4096 + scolb;
  const signed char* b1Src = Bp + (long long)(1024 + bn * 128 + srow) * 4096 + scolb;
  const int ldsW = wv * 1024;

  const int l15 = ln & 15, l4 = ln >> 4;
  int aOff[4], bOff[2];
#pragma unroll
  for (int f = 0; f < 4; ++f) {
    int r = wr * 64 + f * 16 + l15;
    aOff[f] = r * 64 + (l4 ^ ((r >> 1) & 3)) * 16;
  }
#pragma unroll
  for (int g = 0; g < 2; ++g) {
    int r = wc * 32 + g * 16 + l15;
    bOff[g] = r * 64 + (l4 ^ ((r >> 1) & 3)) * 16;
  }

  v4i acc[2][4][2];
#pragma unroll
  for (int L = 0; L < 2; ++L)
#pragma unroll
    for (int f = 0; f < 4; ++f)
#pragma unroll
      for (int g = 0; g < 2; ++g) acc[L][f][g] = (v4i){0, 0, 0, 0};

  // prologue: stage tiles 0,1 into ring slots 0,1
  gload_lds16(aSrc, &As[ldsW]);
  gload_lds16(b0Src, &Bs0[ldsW]);
  gload_lds16(b1Src, &Bs1[ldsW]);
  gload_lds16(aSrc + 64, &As[8192 + ldsW]);
  gload_lds16(b0Src + 64, &Bs0[8192 + ldsW]);
  gload_lds16(b1Src + 64, &Bs1[8192 + ldsW]);

#pragma unroll 1
  for (int i = 0; i < 64; ++i) {
    if (i < 63) {
      asm volatile("s_waitcnt vmcnt(3)" ::: "memory");
    } else {
      asm volatile("s_waitcnt vmcnt(0)" ::: "memory");
    }
    __builtin_amdgcn_sched_barrier(0);
    __builtin_amdgcn_s_barrier();
    __builtin_amdgcn_sched_barrier(0);

    if (i < 62) {                              // depth-2 prefetch
      const int ii = i + 2;
      const int kc = (ii & 31) * 64, so = (ii >> 5) * 2048;
      const int wb = (ii % 3) * 8192 + ldsW;
      gload_lds16(aSrc + kc, &As[wb]);
      gload_lds16(b0Src + so + kc, &Bs0[wb]);
      gload_lds16(b1Src + so + kc, &Bs1[wb]);
    }

    if (i == 32) {                             // Horner fold between planes
#pragma unroll
      for (int L = 0; L < 2; ++L)
#pragma unroll
        for (int f = 0; f < 4; ++f)
#pragma unroll
          for (int g = 0; g < 2; ++g)
#pragma unroll
            for (int r = 0; r < 4; ++r) acc[L][f][g][r] *= 256;
    }

    const int rb = (i % 3) * 8192;
    v4i a[4], b0[2], b1[2];
#pragma unroll
    for (int f = 0; f < 4; ++f) a[f] = *(const v4i*)&As[rb + aOff[f]];
#pragma unroll
    for (int g = 0; g < 2; ++g) b0[g] = *(const v4i*)&Bs0[rb + bOff[g]];
#pragma unroll
    for (int g = 0; g < 2; ++g) b1[g] = *(const v4i*)&Bs1[rb + bOff[g]];
#pragma unroll
    for (int f = 0; f < 4; ++f)
#pragma unroll
      for (int g = 0; g < 2; ++g) {
        acc[0][f][g] = __builtin_amdgcn_mfma_i32_16x16x64_i8(a[f], b0[g], acc[0][f][g], 0, 0, 0);
        acc[1][f][g] = __builtin_amdgcn_mfma_i32_16x16x64_i8(a[f], b1[g], acc[1][f][g], 0, 0, 0);
      }
  }

  // ---- epilogue: per-wave LIF scan + inline BLAS-order fixup ----
  __builtin_amdgcn_s_barrier();                // ring slots dead; reuse LDS
  float* swm  = (float*)(smem + wv * 8448);    // 64x33 f32 scan tile / W row
  float* curw = swm + 2048;                    // 64 f32 (chain results)
  const int b_global = bm * 2 + wr;            // this wave's batch index
  const int ncol0 = bn * 128 + wc * 32;        // first of 32 cols

#pragma unroll 1
  for (int L = 0; L < 2; ++L) {
    float* spkR = out + (L ? 2LL * REGION : 0);
    float* memR = out + (L ? 3LL * REGION : 1LL * REGION);
    // stage cur -> LDS: t = f*16 + l4*4 + r, n'' = g*16 + l15
#pragma unroll
    for (int f = 0; f < 4; ++f)
#pragma unroll
      for (int g = 0; g < 2; ++g)
#pragma unroll
        for (int r = 0; r < 4; ++r)
          swm[(f * 16 + l4 * 4 + r) * 33 + g * 16 + l15] =
              (float)((double)acc[L][f][g][r] * (1.0 / 1048576.0));
    asm volatile("s_waitcnt lgkmcnt(0)" ::: "memory");

    bool flag = false;
    if (ln < 32) {                             // lane = column n'' = ln
      float m = 0.0f;
#pragma unroll 1
      for (int t = 0; t < 64; ++t) {
        float c = swm[t * 33 + ln];
        float reset = (m > 1.0f) ? 1.0f : 0.0f;
        m = __fsub_rn(__fadd_rn(__fmul_rn(0.9f, m), c), reset);
        flag |= (fabsf(m - 1.0f) < FLAG_EPS);
        int k = t * BN_ELEMS + b_global * 1024 + ncol0 + ln;
        spkR[k] = (m > 1.0f) ? 1.0f : 0.0f;
        memR[k] = m;
      }
    }

    unsigned long long fm = __ballot(flag);    // flagged cols (bits 0..31)
#pragma unroll 1
    while (fm) {
      int col = __builtin_ctzll(fm);
      fm &= fm - 1;
      int n_g = ncol0 + col;
      const float* wrow = (L ? W2 : W1) + (long long)n_g * 2048;
#pragma unroll
      for (int i = 0; i < 8; ++i)              // stage W row (8192B) into swm
        ((float4*)swm)[ln + 64 * i] = ((const float4*)wrow)[ln + 64 * i];
      asm volatile("s_waitcnt lgkmcnt(0)" ::: "memory");

      // lane ln = timestep t; ORIGINAL row = t*256 + b_global
      const unsigned long long* mr = maskR + (long long)(ln * 256 + b_global) * 32;
      float total = 0.0f, pacc = 0.0f;
      bool first = true;
#pragma unroll 1
      for (int c = 0; c < 32; ++c) {
        if (c == 6 || c == 12 || c == 18 || c == 24 || c == 30) {  // k = 384p
          total = first ? pacc : __fadd_rn(total, pacc);
          first = false; pacc = 0.0f;
        }
        unsigned long long msk = mr[c];
        unsigned mlo = (unsigned)msk, mhi = (unsigned)(msk >> 32);
        const float* wb = swm + c * 64;
        while (mlo) {                          // ascending q: exact BLAS order;
          int q = __builtin_ctz(mlo);          // skipping +0.0f adds is bitwise
          mlo &= mlo - 1;                      // identity (pacc never -0)
          pacc = __fadd_rn(pacc, wb[q]);
        }
        while (mhi) {
          int q = __builtin_ctz(mhi);
          mhi &= mhi - 1;
          pacc = __fadd_rn(pacc, wb[32 + q]);
        }
      }
      total = first ? pacc : __fadd_rn(total, pacc);
      curw[ln] = total;
      asm volatile("s_waitcnt lgkmcnt(0)" ::: "memory");

      float m = 0.0f, myspk = 0.0f, mymem = 0.0f;
#pragma unroll 1
      for (int tt = 0; tt < 64; ++tt) {        // lane keeps step tt == ln
        float c2 = curw[tt];
        float reset = (m > 1.0f) ? 1.0f : 0.0f;
        m = __fsub_rn(__fadd_rn(__fmul_rn(0.9f, m), c2), reset);
        if (tt == ln) { myspk = (m > 1.0f) ? 1.0f : 0.0f; mymem = m; }
      }
      int k = ln * BN_ELEMS + b_global * 1024 + n_g;
      spkR[k] = myspk;
      memR[k] = mymem;
    }
  }
}

extern "C" void kernel_launch(void* const* d_in, const int* in_sizes, int n_in,
                              void* d_out, int out_size, void* d_ws, size_t ws_size,
                              hipStream_t stream) {
  const float* spikes = (const float*)d_in[0];
  const float* W1 = (const float*)d_in[1];
  const float* W2 = (const float*)d_in[2];
  float* out = (float*)d_out;
  signed char* Bp = (signed char*)d_ws;                              // 8,388,608 B
  signed char* S  = (signed char*)d_ws + 8388608;                    // 33,554,432 B (S')
  unsigned long long* maskR = (unsigned long long*)((char*)d_ws + 41943040);  // 4MB

  prep_kernel<<<18432, 256, 0, stream>>>(spikes, (int*)S, maskR, W1, W2, Bp);
  gemm_fused<<<1024, 512, 0, stream>>>(S, Bp, maskR, W1, W2, out);
}

// Round 22
// 475.655 us; speedup vs baseline: 1.1141x; 1.1141x over previous
//
#include <hip/hip_runtime.h>
#include <hip/hip_bf16.h>
#include <stdint.h>

// SNN forward v8 = v7 with the rule-#20 fix: the v7 epilogue iterated layers
// with `#pragma unroll 1`, making acc[L] runtime-indexed -> compiler demoted
// the WHOLE accumulator array to scratch (VGPR 56, +282MB HBM, 488us). Fully
// unrolling the L loop keeps acc in registers/AGPRs.
//   prep: spikes -> i8 S' (t-reordered: row' = b*64+t) + maskR + W digit-pack.
//   gemm_fused: 2-plane i8 MFMA GEMM (ring-3, depth-2, 1 barrier/iter);
//     M-tile holds complete scan columns (2 b x 64 t) -> f32 LIF scan in the
//     epilogue (LDS-staged, 32 lanes/wave/layer), writes spk/mem directly;
//     flagged columns fixed inline with the r14-validated OpenBLAS-order
//     bit-skip chain (ascending-k, KC=384 folds) -- bit-identical to ref.
// EPS=3e-4 Hoeffding-certified for 2^20 quantization (do not lower).
//
// d_out (f32): [spk1 | mem1 | spk2 | mem2] x 16777216.
// d_ws: Bp 8MB | S' 32MB | maskR 4MB.

#define REGION 16777216
#define BN_ELEMS 262144
#define FLAG_EPS 3e-4f

typedef __attribute__((ext_vector_type(4))) int v4i;

typedef __attribute__((address_space(1))) const void gvoid_t;
typedef __attribute__((address_space(3))) void svoid_t;

__device__ __forceinline__ void gload_lds16(const void* g, void* l) {
  __builtin_amdgcn_global_load_lds((gvoid_t*)g, (svoid_t*)l, 16, 0, 0);
}

// ---- fused prep: blocks 0..2047 cvt(t-reorder)+mask; 2048..18431 digit-pack ----
__global__ void prep_kernel(const float* __restrict__ spikes, int* __restrict__ s4,
                            unsigned long long* __restrict__ maskR,
                            const float* __restrict__ W1, const float* __restrict__ W2,
                            signed char* __restrict__ Bp) {
  int blk = blockIdx.x;
  if (blk < 2048) {
    int id = blk * 256 + threadIdx.x;         // 16384 rows * 32 chunks
    int row = id >> 5, c = id & 31;           // row = t*256 + b
    int t = row >> 8, b = row & 255;
    int rowp = b * 64 + t;                    // reordered row'
    const float4* p = (const float4*)(spikes + (long long)row * 2048 + c * 64);
    unsigned long long m = 0;
    int* sd = s4 + (rowp * 2048 + c * 64) / 4;
#pragma unroll
    for (int q = 0; q < 16; ++q) {
      float4 v = p[q];
      int b0 = (v.x != 0.f), b1 = (v.y != 0.f), b2 = (v.z != 0.f), b3 = (v.w != 0.f);
      sd[q] = b0 | (b1 << 8) | (b2 << 16) | (b3 << 24);
      m |= (unsigned long long)b0 << (4 * q);
      m |= (unsigned long long)b1 << (4 * q + 1);
      m |= (unsigned long long)b2 << (4 * q + 2);
      m |= (unsigned long long)b3 << (4 * q + 3);
    }
    maskR[(long long)row * 32 + c] = m;       // masks stay ORIGINAL-row indexed
  } else {
    int idx = (blk - 2048) * 256 + threadIdx.x;   // 2048*2048
    int n = idx >> 11, k = idx & 2047;
    float w = (n < 1024) ? W1[n * 2048 + k] : W2[(n - 1024) * 2048 + k];
    int V = (int)rintf(w * 1048576.0f);       // 2^20; |V| <= 23270
    int d0 = ((V + 128) & 255) - 128;
    int d1 = (V - d0) >> 8;                   // |d1| <= 91
    signed char* row = Bp + (long long)n * 4096;
    row[k]        = (signed char)d1;   // seg 0
    row[2048 + k] = (signed char)d0;   // seg 1
  }
}

// ---- fused GEMM + scan + inline fixup ----
__global__ __launch_bounds__(512) void gemm_fused(const signed char* __restrict__ S,
                                                  const signed char* __restrict__ Bp,
                                                  const unsigned long long* __restrict__ maskR,
                                                  const float* __restrict__ W1,
                                                  const float* __restrict__ W2,
                                                  float* __restrict__ out) {
  __shared__ __align__(16) signed char smem[73728];   // As|Bs0|Bs1, 24KB each
  signed char* As  = smem;
  signed char* Bs0 = smem + 24576;
  signed char* Bs1 = smem + 49152;
  const int tid = threadIdx.x;
  const int wv = tid >> 6, ln = tid & 63;

  int bid = blockIdx.x;                        // XCD swizzle (1024 = 8*128)
  int swz = (bid & 7) * 128 + (bid >> 3);
  const int bm = swz >> 3;    // 0..127
  const int bn = swz & 7;     // 0..7
  const int wr = wv >> 2, wc = wv & 3;         // 2M x 4N waves

  const int srow = wv * 16 + (ln >> 2);
  const int scolb = ((ln & 3) ^ ((srow >> 1) & 3)) * 16;   // pre-inverse swizzle
  const signed char* aSrc  = S  + (long long)(bm * 128 + srow) * 2048 + scolb;
  const signed char* b0Src = Bp + (long long)(bn * 128 + srow) * 4096 + scolb;
  const signed char* b1Src = Bp + (long long)(1024 + bn * 128 + srow) * 4096 + scolb;
  const int ldsW = wv * 1024;

  const int l15 = ln & 15, l4 = ln >> 4;
  int aOff[4], bOff[2];
#pragma unroll
  for (int f = 0; f < 4; ++f) {
    int r = wr * 64 + f * 16 + l15;
    aOff[f] = r * 64 + (l4 ^ ((r >> 1) & 3)) * 16;
  }
#pragma unroll
  for (int g = 0; g < 2; ++g) {
    int r = wc * 32 + g * 16 + l15;
    bOff[g] = r * 64 + (l4 ^ ((r >> 1) & 3)) * 16;
  }

  v4i acc[2][4][2];
#pragma unroll
  for (int L = 0; L < 2; ++L)
#pragma unroll
    for (int f = 0; f < 4; ++f)
#pragma unroll
      for (int g = 0; g < 2; ++g) acc[L][f][g] = (v4i){0, 0, 0, 0};

  // prologue: stage tiles 0,1 into ring slots 0,1
  gload_lds16(aSrc, &As[ldsW]);
  gload_lds16(b0Src, &Bs0[ldsW]);
  gload_lds16(b1Src, &Bs1[ldsW]);
  gload_lds16(aSrc + 64, &As[8192 + ldsW]);
  gload_lds16(b0Src + 64, &Bs0[8192 + ldsW]);
  gload_lds16(b1Src + 64, &Bs1[8192 + ldsW]);

#pragma unroll 1
  for (int i = 0; i < 64; ++i) {
    if (i < 63) {
      asm volatile("s_waitcnt vmcnt(3)" ::: "memory");
    } else {
      asm volatile("s_waitcnt vmcnt(0)" ::: "memory");
    }
    __builtin_amdgcn_sched_barrier(0);
    __builtin_amdgcn_s_barrier();
    __builtin_amdgcn_sched_barrier(0);

    if (i < 62) {                              // depth-2 prefetch
      const int ii = i + 2;
      const int kc = (ii & 31) * 64, so = (ii >> 5) * 2048;
      const int wb = (ii % 3) * 8192 + ldsW;
      gload_lds16(aSrc + kc, &As[wb]);
      gload_lds16(b0Src + so + kc, &Bs0[wb]);
      gload_lds16(b1Src + so + kc, &Bs1[wb]);
    }

    if (i == 32) {                             // Horner fold between planes
#pragma unroll
      for (int L = 0; L < 2; ++L)
#pragma unroll
        for (int f = 0; f < 4; ++f)
#pragma unroll
          for (int g = 0; g < 2; ++g)
#pragma unroll
            for (int r = 0; r < 4; ++r) acc[L][f][g][r] *= 256;
    }

    const int rb = (i % 3) * 8192;
    v4i a[4], b0[2], b1[2];
#pragma unroll
    for (int f = 0; f < 4; ++f) a[f] = *(const v4i*)&As[rb + aOff[f]];
#pragma unroll
    for (int g = 0; g < 2; ++g) b0[g] = *(const v4i*)&Bs0[rb + bOff[g]];
#pragma unroll
    for (int g = 0; g < 2; ++g) b1[g] = *(const v4i*)&Bs1[rb + bOff[g]];
#pragma unroll
    for (int f = 0; f < 4; ++f)
#pragma unroll
      for (int g = 0; g < 2; ++g) {
        acc[0][f][g] = __builtin_amdgcn_mfma_i32_16x16x64_i8(a[f], b0[g], acc[0][f][g], 0, 0, 0);
        acc[1][f][g] = __builtin_amdgcn_mfma_i32_16x16x64_i8(a[f], b1[g], acc[1][f][g], 0, 0, 0);
      }
  }

  // ---- epilogue: per-wave LIF scan + inline BLAS-order fixup ----
  // FULLY UNROLLED over L (compile-time acc indexing -> registers; rule #20).
  __builtin_amdgcn_s_barrier();                // ring slots dead; reuse LDS
  float* swm  = (float*)(smem + wv * 8448);    // 64x33 f32 scan tile / W row
  float* curw = swm + 2048;                    // 64 f32 (chain results)
  const int b_global = bm * 2 + wr;            // this wave's batch index
  const int ncol0 = bn * 128 + wc * 32;        // first of 32 cols

#pragma unroll
  for (int L = 0; L < 2; ++L) {
    float* spkR = out + (L ? 2LL * REGION : 0);
    float* memR = out + (L ? 3LL * REGION : 1LL * REGION);
    // stage cur -> LDS: t = f*16 + l4*4 + r, n'' = g*16 + l15
#pragma unroll
    for (int f = 0; f < 4; ++f)
#pragma unroll
      for (int g = 0; g < 2; ++g)
#pragma unroll
        for (int r = 0; r < 4; ++r)
          swm[(f * 16 + l4 * 4 + r) * 33 + g * 16 + l15] =
              (float)((double)acc[L][f][g][r] * (1.0 / 1048576.0));
    asm volatile("s_waitcnt lgkmcnt(0)" ::: "memory");

    bool flag = false;
    if (ln < 32) {                             // lane = column n'' = ln
      float m = 0.0f;
#pragma unroll 4
      for (int t = 0; t < 64; ++t) {           // unroll 4: batch LDS reads
        float c = swm[t * 33 + ln];
        float reset = (m > 1.0f) ? 1.0f : 0.0f;
        m = __fsub_rn(__fadd_rn(__fmul_rn(0.9f, m), c), reset);
        flag |= (fabsf(m - 1.0f) < FLAG_EPS);
        int k = t * BN_ELEMS + b_global * 1024 + ncol0 + ln;
        spkR[k] = (m > 1.0f) ? 1.0f : 0.0f;
        memR[k] = m;
      }
    }

    unsigned long long fm = __ballot(flag);    // flagged cols (bits 0..31)
#pragma unroll 1
    while (fm) {
      int col = __builtin_ctzll(fm);
      fm &= fm - 1;
      int n_g = ncol0 + col;
      const float* wrow = (L ? W2 : W1) + (long long)n_g * 2048;
#pragma unroll
      for (int i = 0; i < 8; ++i)              // stage W row (8192B) into swm
        ((float4*)swm)[ln + 64 * i] = ((const float4*)wrow)[ln + 64 * i];
      asm volatile("s_waitcnt lgkmcnt(0)" ::: "memory");

      // lane ln = timestep t; ORIGINAL row = t*256 + b_global
      const unsigned long long* mr = maskR + (long long)(ln * 256 + b_global) * 32;
      float total = 0.0f, pacc = 0.0f;
      bool first = true;
#pragma unroll 1
      for (int c = 0; c < 32; ++c) {
        if (c == 6 || c == 12 || c == 18 || c == 24 || c == 30) {  // k = 384p
          total = first ? pacc : __fadd_rn(total, pacc);
          first = false; pacc = 0.0f;
        }
        unsigned long long msk = mr[c];
        unsigned mlo = (unsigned)msk, mhi = (unsigned)(msk >> 32);
        const float* wb = swm + c * 64;
        while (mlo) {                          // ascending q: exact BLAS order;
          int q = __builtin_ctz(mlo);          // skipping +0.0f adds is bitwise
          mlo &= mlo - 1;                      // identity (pacc never -0)
          pacc = __fadd_rn(pacc, wb[q]);
        }
        while (mhi) {
          int q = __builtin_ctz(mhi);
          mhi &= mhi - 1;
          pacc = __fadd_rn(pacc, wb[32 + q]);
        }
      }
      total = first ? pacc : __fadd_rn(total, pacc);
      curw[ln] = total;
      asm volatile("s_waitcnt lgkmcnt(0)" ::: "memory");

      float m = 0.0f, myspk = 0.0f, mymem = 0.0f;
#pragma unroll 1
      for (int tt = 0; tt < 64; ++tt) {        // lane keeps step tt == ln
        float c2 = curw[tt];
        float reset = (m > 1.0f) ? 1.0f : 0.0f;
        m = __fsub_rn(__fadd_rn(__fmul_rn(0.9f, m), c2), reset);
        if (tt == ln) { myspk = (m > 1.0f) ? 1.0f : 0.0f; mymem = m; }
      }
      int k = ln * BN_ELEMS + b_global * 1024 + n_g;
      spkR[k] = myspk;
      memR[k] = mymem;
    }
  }
}

extern "C" void kernel_launch(void* const* d_in, const int* in_sizes, int n_in,
                              void* d_out, int out_size, void* d_ws, size_t ws_size,
                              hipStream_t stream) {
  const float* spikes = (const float*)d_in[0];
  const float* W1 = (const float*)d_in[1];
  const float* W2 = (const float*)d_in[2];
  float* out = (float*)d_out;
  signed char* Bp = (signed char*)d_ws;                              // 8,388,608 B
  signed char* S  = (signed char*)d_ws + 8388608;                    // 33,554,432 B (S')
  unsigned long long* maskR = (unsigned long long*)((char*)d_ws + 41943040);  // 4MB

  prep_kernel<<<18432, 256, 0, stream>>>(spikes, (int*)S, maskR, W1, W2, Bp);
  gemm_fused<<<1024, 512, 0, stream>>>(S, Bp, maskR, W1, W2, out);
}

// Round 23
// 350.622 us; speedup vs baseline: 1.5114x; 1.3566x over previous
//
#include <hip/hip_runtime.h>
#include <hip/hip_bf16.h>
#include <stdint.h>

// SNN forward v9 = v6 (r20, best @345us) + 4-chain lif_flag (2 cols x 2
// layers per thread -> 2x memory-level parallelism on the latency-limited
// scan). Fused-epilogue variants (r21/r22) empirically regressed (+90..130us:
// 32-lane scattered 128B stores, no overlap) -> reverted.
// Pipeline: prep (cvt+mask+digit-pack) -> 2-plane i8 MFMA GEMM (ring-3,
// depth-2 prefetch, counted vmcnt(3), 1 barrier/iter) -> lif_flag (EPS=3e-4,
// Hoeffding-certified; do not lower) -> bit-skip OpenBLAS-order fixup
// (ascending-k chains, KC=384 folds; bit-identical to the np ref's BLAS).
//
// d_out (f32): [spk1 | mem1 | spk2 | mem2] x 16777216. GEMM writes cur f32
// into spk regions; lif_flag overwrites; flagged cols recomputed bit-exact.
// d_ws: Bp 8MB | S 32MB | maskR 4MB | list 2MB | count.

#define REGION 16777216
#define BN_ELEMS 262144
#define FLAG_EPS 3e-4f

typedef __attribute__((ext_vector_type(4))) int v4i;

typedef __attribute__((address_space(1))) const void gvoid_t;
typedef __attribute__((address_space(3))) void svoid_t;

__device__ __forceinline__ void gload_lds16(const void* g, void* l) {
  __builtin_amdgcn_global_load_lds((gvoid_t*)g, (svoid_t*)l, 16, 0, 0);
}

// ---- fused prep: blocks 0..2047 cvt+mask (+count=0); 2048..18431 digit-pack ----
__global__ void prep_kernel(const float* __restrict__ spikes, int* __restrict__ s4,
                            unsigned long long* __restrict__ maskR,
                            int* __restrict__ count,
                            const float* __restrict__ W1, const float* __restrict__ W2,
                            signed char* __restrict__ Bp) {
  int blk = blockIdx.x;
  if (blk < 2048) {
    int id = blk * 256 + threadIdx.x;         // 16384 rows * 32 chunks
    if (id == 0) *count = 0;
    int row = id >> 5, c = id & 31;
    const float4* p = (const float4*)(spikes + (long long)row * 2048 + c * 64);
    unsigned long long m = 0;
    int* sd = s4 + (row * 2048 + c * 64) / 4;
#pragma unroll
    for (int q = 0; q < 16; ++q) {
      float4 v = p[q];
      int b0 = (v.x != 0.f), b1 = (v.y != 0.f), b2 = (v.z != 0.f), b3 = (v.w != 0.f);
      sd[q] = b0 | (b1 << 8) | (b2 << 16) | (b3 << 24);
      m |= (unsigned long long)b0 << (4 * q);
      m |= (unsigned long long)b1 << (4 * q + 1);
      m |= (unsigned long long)b2 << (4 * q + 2);
      m |= (unsigned long long)b3 << (4 * q + 3);
    }
    maskR[(long long)row * 32 + c] = m;
  } else {
    int idx = (blk - 2048) * 256 + threadIdx.x;   // 2048*2048
    int n = idx >> 11, k = idx & 2047;
    float w = (n < 1024) ? W1[n * 2048 + k] : W2[(n - 1024) * 2048 + k];
    int V = (int)rintf(w * 1048576.0f);       // 2^20; |V| <= 23270
    int d0 = ((V + 128) & 255) - 128;
    int d1 = (V - d0) >> 8;                   // |d1| <= 91
    signed char* row = Bp + (long long)n * 4096;
    row[k]        = (signed char)d1;   // seg 0
    row[2048 + k] = (signed char)d0;   // seg 1
  }
}

// ---- 2-plane i8 GEMM, ring-3, depth-2 prefetch, 1 barrier/iter (r20) ----
__global__ __launch_bounds__(512) void gemm_snn(const signed char* __restrict__ S,
                                                const signed char* __restrict__ Bp,
                                                float* __restrict__ out) {
  __shared__ __align__(16) signed char As[3 * 8192];
  __shared__ __align__(16) signed char Bs0[3 * 8192];
  __shared__ __align__(16) signed char Bs1[3 * 8192];
  const int tid = threadIdx.x;
  const int wv = tid >> 6, ln = tid & 63;

  int bid = blockIdx.x;                        // XCD swizzle (1024 = 8*128)
  int swz = (bid & 7) * 128 + (bid >> 3);
  const int bm = swz >> 3;    // 0..127
  const int bn = swz & 7;     // 0..7
  const int wr = wv >> 2, wc = wv & 3;         // 2M x 4N waves

  const int srow = wv * 16 + (ln >> 2);
  const int scolb = ((ln & 3) ^ ((srow >> 1) & 3)) * 16;   // pre-inverse swizzle
  const signed char* aSrc  = S  + (long long)(bm * 128 + srow) * 2048 + scolb;
  const signed char* b0Src = Bp + (long long)(bn * 128 + srow) * 4096 + scolb;
  const signed char* b1Src = Bp + (long long)(1024 + bn * 128 + srow) * 4096 + scolb;
  const int ldsW = wv * 1024;                  // wave-uniform LDS dst base

  const int l15 = ln & 15, l4 = ln >> 4;
  int aOff[4], bOff[2];
#pragma unroll
  for (int f = 0; f < 4; ++f) {
    int r = wr * 64 + f * 16 + l15;
    aOff[f] = r * 64 + (l4 ^ ((r >> 1) & 3)) * 16;   // swizzled read
  }
#pragma unroll
  for (int g = 0; g < 2; ++g) {
    int r = wc * 32 + g * 16 + l15;
    bOff[g] = r * 64 + (l4 ^ ((r >> 1) & 3)) * 16;
  }

  v4i acc[2][4][2];
#pragma unroll
  for (int L = 0; L < 2; ++L)
#pragma unroll
    for (int f = 0; f < 4; ++f)
#pragma unroll
      for (int g = 0; g < 2; ++g) acc[L][f][g] = (v4i){0, 0, 0, 0};

  // prologue: stage tiles 0 and 1 into slots 0,1
  gload_lds16(aSrc, &As[ldsW]);
  gload_lds16(b0Src, &Bs0[ldsW]);
  gload_lds16(b1Src, &Bs1[ldsW]);
  gload_lds16(aSrc + 64, &As[8192 + ldsW]);
  gload_lds16(b0Src + 64, &Bs0[8192 + ldsW]);
  gload_lds16(b1Src + 64, &Bs1[8192 + ldsW]);

#pragma unroll 1
  for (int i = 0; i < 64; ++i) {
    if (i < 63) {
      asm volatile("s_waitcnt vmcnt(3)" ::: "memory");  // tile i landed
    } else {
      asm volatile("s_waitcnt vmcnt(0)" ::: "memory");
    }
    __builtin_amdgcn_sched_barrier(0);
    __builtin_amdgcn_s_barrier();              // single barrier per iteration
    __builtin_amdgcn_sched_barrier(0);

    if (i < 62) {                              // depth-2: issue tile i+2 now
      const int ii = i + 2;
      const int kc = (ii & 31) * 64, so = (ii >> 5) * 2048;
      const int wb = (ii % 3) * 8192 + ldsW;
      gload_lds16(aSrc + kc, &As[wb]);
      gload_lds16(b0Src + so + kc, &Bs0[wb]);
      gload_lds16(b1Src + so + kc, &Bs1[wb]);
    }

    if (i == 32) {                             // Horner fold between planes
#pragma unroll
      for (int L = 0; L < 2; ++L)
#pragma unroll
        for (int f = 0; f < 4; ++f)
#pragma unroll
          for (int g = 0; g < 2; ++g)
#pragma unroll
            for (int r = 0; r < 4; ++r) acc[L][f][g][r] *= 256;
    }

    const int rb = (i % 3) * 8192;
    v4i a[4], b0[2], b1[2];
#pragma unroll
    for (int f = 0; f < 4; ++f) a[f] = *(const v4i*)&As[rb + aOff[f]];
#pragma unroll
    for (int g = 0; g < 2; ++g) b0[g] = *(const v4i*)&Bs0[rb + bOff[g]];
#pragma unroll
    for (int g = 0; g < 2; ++g) b1[g] = *(const v4i*)&Bs1[rb + bOff[g]];
#pragma unroll
    for (int f = 0; f < 4; ++f)
#pragma unroll
      for (int g = 0; g < 2; ++g) {
        acc[0][f][g] = __builtin_amdgcn_mfma_i32_16x16x64_i8(a[f], b0[g], acc[0][f][g], 0, 0, 0);
        acc[1][f][g] = __builtin_amdgcn_mfma_i32_16x16x64_i8(a[f], b1[g], acc[1][f][g], 0, 0, 0);
      }
  }

#pragma unroll
  for (int L = 0; L < 2; ++L) {
    float* spkBase = out + (L ? 2LL * REGION : 0);
#pragma unroll
    for (int f = 0; f < 4; ++f)
#pragma unroll
      for (int g = 0; g < 2; ++g) {
        int row = bm * 128 + wr * 64 + f * 16 + l4 * 4;
        int col = bn * 128 + wc * 32 + g * 16 + l15;
#pragma unroll
        for (int r = 0; r < 4; ++r)
          spkBase[(long long)(row + r) * 1024 + col] =
              (float)((double)acc[L][f][g][r] * (1.0 / 1048576.0));
      }
  }
}

// ---- f32 LIF scan: 4 chains/thread (2 cols x 2 layers) for 2x MLP ----
__global__ void lif_flag(float* __restrict__ out, int* __restrict__ list,
                         int* __restrict__ count) {
  int j0 = blockIdx.x * 256 + threadIdx.x;    // 0..131071
  int j1 = j0 + 131072;
  float* spk1 = out;
  float* mem1 = out + 1LL * REGION;
  float* spk2 = out + 2LL * REGION;
  float* mem2 = out + 3LL * REGION;
  float ma0 = 0.0f, mb0 = 0.0f, ma1 = 0.0f, mb1 = 0.0f;
  bool fa0 = false, fb0 = false, fa1 = false, fb1 = false;
#pragma unroll 4
  for (int t = 0; t < 64; ++t) {
    int k0 = t * BN_ELEMS + j0;
    int k1 = t * BN_ELEMS + j1;
    float ca0 = spk1[k0], ca1 = spk1[k1];
    float cb0 = spk2[k0], cb1 = spk2[k1];
    float ra0 = (ma0 > 1.0f) ? 1.0f : 0.0f;
    float ra1 = (ma1 > 1.0f) ? 1.0f : 0.0f;
    float rb0 = (mb0 > 1.0f) ? 1.0f : 0.0f;
    float rb1 = (mb1 > 1.0f) ? 1.0f : 0.0f;
    ma0 = __fsub_rn(__fadd_rn(__fmul_rn(0.9f, ma0), ca0), ra0);
    ma1 = __fsub_rn(__fadd_rn(__fmul_rn(0.9f, ma1), ca1), ra1);
    mb0 = __fsub_rn(__fadd_rn(__fmul_rn(0.9f, mb0), cb0), rb0);
    mb1 = __fsub_rn(__fadd_rn(__fmul_rn(0.9f, mb1), cb1), rb1);
    fa0 |= (fabsf(ma0 - 1.0f) < FLAG_EPS);
    fa1 |= (fabsf(ma1 - 1.0f) < FLAG_EPS);
    fb0 |= (fabsf(mb0 - 1.0f) < FLAG_EPS);
    fb1 |= (fabsf(mb1 - 1.0f) < FLAG_EPS);
    spk1[k0] = (ma0 > 1.0f) ? 1.0f : 0.0f;
    spk1[k1] = (ma1 > 1.0f) ? 1.0f : 0.0f;
    mem1[k0] = ma0;
    mem1[k1] = ma1;
    spk2[k0] = (mb0 > 1.0f) ? 1.0f : 0.0f;
    spk2[k1] = (mb1 > 1.0f) ? 1.0f : 0.0f;
    mem2[k0] = mb0;
    mem2[k1] = mb1;
  }
  if (fa0) { int q = atomicAdd(count, 1); list[q] = j0; }
  if (fa1) { int q = atomicAdd(count, 1); list[q] = j1; }
  if (fb0) { int q = atomicAdd(count, 1); list[q] = BN_ELEMS + j0; }
  if (fb1) { int q = atomicAdd(count, 1); list[q] = BN_ELEMS + j1; }
}

// ---- fixup: 4 waves/block, one column/wave, bit-skip BLAS-order chain ----
__global__ __launch_bounds__(256) void fixup_kernel(
    const unsigned long long* __restrict__ maskR,
    const float* __restrict__ W1, const float* __restrict__ W2,
    const int* __restrict__ list, const int* __restrict__ count,
    float* __restrict__ out) {
  __shared__ float ws[4][2048];
  __shared__ float curs[4][64];
  const int wv = threadIdx.x >> 6, ln = threadIdx.x & 63;
  const int cnt = *count;
  for (int li = blockIdx.x * 4 + wv; li < cnt; li += gridDim.x * 4) {
    int idx = list[li];
    int layer = idx >> 18;
    int j = idx & (BN_ELEMS - 1);
    int n = j & 1023, b = j >> 10;
    const float* wrow = (layer ? W2 : W1) + (long long)n * 2048;
#pragma unroll
    for (int i = 0; i < 8; ++i)
      ((float4*)ws[wv])[ln + 64 * i] = ((const float4*)wrow)[ln + 64 * i];
    asm volatile("s_waitcnt lgkmcnt(0)" ::: "memory");   // wave-local LDS fence

    const unsigned long long* mr = maskR + (long long)(ln * 256 + b) * 32;
    float total = 0.0f, pacc = 0.0f;
    bool first = true;
#pragma unroll 1
    for (int c = 0; c < 32; ++c) {
      if (c == 6 || c == 12 || c == 18 || c == 24 || c == 30) {  // k = 384p
        total = first ? pacc : __fadd_rn(total, pacc);
        first = false; pacc = 0.0f;
      }
      unsigned long long msk = mr[c];
      unsigned mlo = (unsigned)msk, mhi = (unsigned)(msk >> 32);
      const float* wb = ws[wv] + c * 64;
      while (mlo) {                            // ascending q: exact BLAS order;
        int q = __builtin_ctz(mlo);            // skipping +0.0f adds is bitwise
        mlo &= mlo - 1;                        // identity (pacc never -0)
        pacc = __fadd_rn(pacc, wb[q]);
      }
      while (mhi) {
        int q = __builtin_ctz(mhi);
        mhi &= mhi - 1;
        pacc = __fadd_rn(pacc, wb[32 + q]);
      }
    }
    total = first ? pacc : __fadd_rn(total, pacc);
    curs[wv][ln] = total;
    asm volatile("s_waitcnt lgkmcnt(0)" ::: "memory");

    float m = 0.0f, myspk = 0.0f, mymem = 0.0f;
#pragma unroll 1
    for (int tt = 0; tt < 64; ++tt) {
      float c2 = curs[wv][tt];
      float reset = (m > 1.0f) ? 1.0f : 0.0f;
      m = __fsub_rn(__fadd_rn(__fmul_rn(0.9f, m), c2), reset);
      if (tt == ln) { myspk = (m > 1.0f) ? 1.0f : 0.0f; mymem = m; }
    }
    float* spkR = out + (layer ? 2LL * REGION : 0);
    float* memR = out + (layer ? 3LL * REGION : 1LL * REGION);
    spkR[ln * BN_ELEMS + j] = myspk;
    memR[ln * BN_ELEMS + j] = mymem;
  }
}

extern "C" void kernel_launch(void* const* d_in, const int* in_sizes, int n_in,
                              void* d_out, int out_size, void* d_ws, size_t ws_size,
                              hipStream_t stream) {
  const float* spikes = (const float*)d_in[0];
  const float* W1 = (const float*)d_in[1];
  const float* W2 = (const float*)d_in[2];
  float* out = (float*)d_out;
  signed char* Bp = (signed char*)d_ws;                              // 8,388,608 B
  signed char* S  = (signed char*)d_ws + 8388608;                    // 33,554,432 B
  unsigned long long* maskR = (unsigned long long*)((char*)d_ws + 41943040);  // 4MB
  int* list  = (int*)((char*)d_ws + 46137344);                       // 2MB
  int* count = (int*)((char*)d_ws + 48234496);

  prep_kernel<<<18432, 256, 0, stream>>>(spikes, (int*)S, maskR, count, W1, W2, Bp);
  gemm_snn<<<1024, 512, 0, stream>>>(S, Bp, out);
  lif_flag<<<512, 256, 0, stream>>>(out, list, count);
  fixup_kernel<<<4096, 256, 0, stream>>>(maskR, W1, W2, list, count, out);
}